// Round 1
// baseline (8306.392 us; speedup 1.0000x reference)
//
#include <hip/hip_runtime.h>

#define N_NODES 100000
#define N_EDGES 1600000
#define INP 16
#define EMB 32
#define ATTN 32
#define D0 48
#define RREL 200
#define NB 4
#define GAMMA_C 10.0f

// ---------------- node prep: h0 = concat(feat, embed[node_ids]); a1 = h0@A1w.T+b; a2 likewise
__global__ __launch_bounds__(256) void k_node_prep(
    const float* __restrict__ feat, const int* __restrict__ node_ids,
    const float* __restrict__ embed,
    const float* __restrict__ A1w, const float* __restrict__ A1b,
    const float* __restrict__ A2w, const float* __restrict__ A2b,
    float* __restrict__ h0, float* __restrict__ a1, float* __restrict__ a2) {
  int n = blockIdx.x * blockDim.x + threadIdx.x;
  if (n >= N_NODES) return;
  float h[D0];
  const float4* f4 = reinterpret_cast<const float4*>(feat + (size_t)n * INP);
  #pragma unroll
  for (int i = 0; i < INP / 4; ++i) {
    float4 v = f4[i];
    h[4*i+0] = v.x; h[4*i+1] = v.y; h[4*i+2] = v.z; h[4*i+3] = v.w;
  }
  int nid = node_ids[n];
  const float4* e4 = reinterpret_cast<const float4*>(embed + (size_t)nid * EMB);
  #pragma unroll
  for (int i = 0; i < EMB / 4; ++i) {
    float4 v = e4[i];
    h[INP+4*i+0] = v.x; h[INP+4*i+1] = v.y; h[INP+4*i+2] = v.z; h[INP+4*i+3] = v.w;
  }
  float4* h04 = reinterpret_cast<float4*>(h0 + (size_t)n * D0);
  #pragma unroll
  for (int i = 0; i < D0 / 4; ++i) {
    h04[i] = make_float4(h[4*i], h[4*i+1], h[4*i+2], h[4*i+3]);
  }
  // a1[o] = A1b[o] + sum_i h[i] * A1w[o*D0+i]   (weights thread-uniform -> scalar loads)
  for (int o = 0; o < ATTN; ++o) {
    float acc = A1b[o];
    #pragma unroll
    for (int i = 0; i < D0; ++i) acc += h[i] * A1w[o * D0 + i];
    a1[(size_t)n * ATTN + o] = acc;
  }
  for (int o = 0; o < ATTN; ++o) {
    float acc = A2b[o];
    #pragma unroll
    for (int i = 0; i < D0; ++i) acc += h[i] * A2w[o * D0 + i];
    a2[(size_t)n * ATTN + o] = acc;
  }
}

// ---------------- per-edge attention weight
__global__ __launch_bounds__(256) void k_alpha(
    const int* __restrict__ src, const int* __restrict__ dst, const int* __restrict__ typ,
    const float* __restrict__ a1, const float* __restrict__ a2,
    const float* __restrict__ rel, float* __restrict__ alpha) {
  int e = blockIdx.x * blockDim.x + threadIdx.x;
  if (e >= N_EDGES) return;
  int s = src[e], d = dst[e], t = typ[e];
  const float4* p1 = reinterpret_cast<const float4*>(a1 + (size_t)s * ATTN);
  const float4* p2 = reinterpret_cast<const float4*>(a2 + (size_t)d * ATTN);
  const float4* pr = reinterpret_cast<const float4*>(rel + (size_t)t * ATTN);
  float ss = 0.f;
  #pragma unroll
  for (int j = 0; j < ATTN / 4; ++j) {
    float4 x1 = p1[j], x2 = p2[j], xr = pr[j];
    float dx = x1.x + xr.x - x2.x; ss += dx * dx;
    dx = x1.y + xr.y - x2.y; ss += dx * dx;
    dx = x1.z + xr.z - x2.z; ss += dx * dx;
    dx = x1.w + xr.w - x2.w; ss += dx * dx;
  }
  float nrm = sqrtf(ss + 1e-12f);
  alpha[e] = 1.f / (1.f + __expf(nrm - GAMMA_C));
}

// ---------------- per-node layer compute: hb[n,b,:] = h@bases[b]; outbuf[n,:] = h@sloop + bias
template <int DIN, bool RELU_IN>
__global__ __launch_bounds__(256) void k_node_layer(
    const float* __restrict__ hin, const float* __restrict__ bases,
    const float* __restrict__ sloop, const float* __restrict__ bias,
    float* __restrict__ hb, float* __restrict__ outbuf) {
  int n = blockIdx.x * blockDim.x + threadIdx.x;
  if (n >= N_NODES) return;
  float h[DIN];
  const float4* h4 = reinterpret_cast<const float4*>(hin + (size_t)n * DIN);
  #pragma unroll
  for (int i = 0; i < DIN / 4; ++i) {
    float4 v = h4[i];
    if (RELU_IN) {
      v.x = fmaxf(v.x, 0.f); v.y = fmaxf(v.y, 0.f);
      v.z = fmaxf(v.z, 0.f); v.w = fmaxf(v.w, 0.f);
    }
    h[4*i+0] = v.x; h[4*i+1] = v.y; h[4*i+2] = v.z; h[4*i+3] = v.w;
  }
  float acc[EMB];
  for (int b = 0; b < NB; ++b) {
    #pragma unroll
    for (int o = 0; o < EMB; ++o) acc[o] = 0.f;
    for (int i = 0; i < DIN; ++i) {
      float hv = h[i];
      #pragma unroll
      for (int o = 0; o < EMB; ++o) acc[o] += hv * bases[((b * DIN) + i) * EMB + o];
    }
    float4* o4 = reinterpret_cast<float4*>(hb + (size_t)n * (NB * EMB) + b * EMB);
    #pragma unroll
    for (int j = 0; j < EMB / 4; ++j)
      o4[j] = make_float4(acc[4*j], acc[4*j+1], acc[4*j+2], acc[4*j+3]);
  }
  // self-loop + bias
  #pragma unroll
  for (int o = 0; o < EMB; ++o) acc[o] = bias[o];
  for (int i = 0; i < DIN; ++i) {
    float hv = h[i];
    #pragma unroll
    for (int o = 0; o < EMB; ++o) acc[o] += hv * sloop[i * EMB + o];
  }
  float4* ob = reinterpret_cast<float4*>(outbuf + (size_t)n * EMB);
  #pragma unroll
  for (int j = 0; j < EMB / 4; ++j)
    ob[j] = make_float4(acc[4*j], acc[4*j+1], acc[4*j+2], acc[4*j+3]);
}

// ---------------- per-edge gather + weighted message + atomic scatter
__global__ __launch_bounds__(256) void k_edge_agg(
    const int* __restrict__ src, const int* __restrict__ dst, const int* __restrict__ typ,
    const float* __restrict__ wcomp, const float* __restrict__ alpha,
    const float* __restrict__ hb, float* __restrict__ out) {
  int e = blockIdx.x * blockDim.x + threadIdx.x;
  if (e >= N_EDGES) return;
  int s = src[e], d = dst[e], t = typ[e];
  float a = alpha[e];
  float4 w = *reinterpret_cast<const float4*>(wcomp + (size_t)t * NB);
  float w0 = a * w.x, w1 = a * w.y, w2 = a * w.z, w3 = a * w.w;
  const float4* hb4 = reinterpret_cast<const float4*>(hb + (size_t)s * (NB * EMB));
  float* od = out + (size_t)d * EMB;
  #pragma unroll
  for (int j = 0; j < EMB / 4; ++j) {
    float4 x0 = hb4[j], x1 = hb4[8 + j], x2 = hb4[16 + j], x3 = hb4[24 + j];
    float4 m;
    m.x = w0 * x0.x + w1 * x1.x + w2 * x2.x + w3 * x3.x;
    m.y = w0 * x0.y + w1 * x1.y + w2 * x2.y + w3 * x3.y;
    m.z = w0 * x0.z + w1 * x1.z + w2 * x2.z + w3 * x3.z;
    m.w = w0 * x0.w + w1 * x1.w + w2 * x2.w + w3 * x3.w;
    atomicAdd(od + 4*j + 0, m.x);
    atomicAdd(od + 4*j + 1, m.y);
    atomicAdd(od + 4*j + 2, m.z);
    atomicAdd(od + 4*j + 3, m.w);
  }
}

// ---------------- final relu in place
__global__ __launch_bounds__(256) void k_relu(float* __restrict__ x, int n4) {
  int i = blockIdx.x * blockDim.x + threadIdx.x;
  if (i >= n4) return;
  float4* p = reinterpret_cast<float4*>(x) + i;
  float4 v = *p;
  v.x = fmaxf(v.x, 0.f); v.y = fmaxf(v.y, 0.f);
  v.z = fmaxf(v.z, 0.f); v.w = fmaxf(v.w, 0.f);
  *p = v;
}

extern "C" void kernel_launch(void* const* d_in, const int* in_sizes, int n_in,
                              void* d_out, int out_size, void* d_ws, size_t ws_size,
                              hipStream_t stream) {
  const float* feat     = (const float*)d_in[0];
  const int*   node_ids = (const int*)d_in[1];
  const int*   esrc     = (const int*)d_in[2];
  const int*   edst     = (const int*)d_in[3];
  const int*   etyp     = (const int*)d_in[4];
  const float* embed    = (const float*)d_in[5];
  const float* attn_rel = (const float*)d_in[6];
  const float* A1w = (const float*)d_in[7];
  const float* A1b = (const float*)d_in[8];
  const float* A2w = (const float*)d_in[9];
  const float* A2b = (const float*)d_in[10];
  const float* bases0 = (const float*)d_in[11];
  const float* wcomp0 = (const float*)d_in[12];
  const float* sloop0 = (const float*)d_in[13];
  const float* bias0  = (const float*)d_in[14];
  const float* bases1 = (const float*)d_in[15];
  const float* wcomp1 = (const float*)d_in[16];
  const float* sloop1 = (const float*)d_in[17];
  const float* bias1  = (const float*)d_in[18];
  const float* bases2 = (const float*)d_in[19];
  const float* wcomp2 = (const float*)d_in[20];
  const float* sloop2 = (const float*)d_in[21];
  const float* bias2  = (const float*)d_in[22];

  float* ws = (float*)d_ws;
  float* h0    = ws;                       // N*48   = 4.8M floats
  float* HB    = ws + 4800000;             // N*128  = 12.8M floats
  float* bufA  = ws + 17600000;            // N*32   = 3.2M floats
  float* bufB  = ws + 20800000;            // N*32   = 3.2M floats
  float* alpha = ws + 24000000;            // E      = 1.6M floats
  // a1/a2 alias the HB region: dead before HB is first written (layer0 node kernel)
  float* a1 = HB;
  float* a2 = HB + 3200000;
  float* out = (float*)d_out;

  dim3 blk(256);
  int nb_n = (N_NODES + 255) / 256;
  int nb_e = (N_EDGES + 255) / 256;

  k_node_prep<<<nb_n, blk, 0, stream>>>(feat, node_ids, embed, A1w, A1b, A2w, A2b, h0, a1, a2);
  k_alpha<<<nb_e, blk, 0, stream>>>(esrc, edst, etyp, a1, a2, attn_rel, alpha);

  // layer 0 (din=48, no relu on input)
  k_node_layer<D0, false><<<nb_n, blk, 0, stream>>>(h0, bases0, sloop0, bias0, HB, bufA);
  k_edge_agg<<<nb_e, blk, 0, stream>>>(esrc, edst, etyp, wcomp0, alpha, HB, bufA);

  // layer 1 (din=32, relu on input)
  k_node_layer<EMB, true><<<nb_n, blk, 0, stream>>>(bufA, bases1, sloop1, bias1, HB, bufB);
  k_edge_agg<<<nb_e, blk, 0, stream>>>(esrc, edst, etyp, wcomp1, alpha, HB, bufB);

  // layer 2 (din=32, relu on input) -> write directly into d_out
  k_node_layer<EMB, true><<<nb_n, blk, 0, stream>>>(bufB, bases2, sloop2, bias2, HB, out);
  k_edge_agg<<<nb_e, blk, 0, stream>>>(esrc, edst, etyp, wcomp2, alpha, HB, out);

  k_relu<<<(N_NODES * EMB / 4 + 255) / 256, blk, 0, stream>>>(out, N_NODES * EMB / 4);
}

// Round 2
// 845.352 us; speedup vs baseline: 9.8260x; 9.8260x over previous
//
#include <hip/hip_runtime.h>

#define N_NODES 100000
#define N_EDGES 1600000
#define INP 16
#define EMB 32
#define ATTN 32
#define D0 48
#define RREL 200
#define NB 4
#define GAMMA_C 10.0f

#define SCAN_T 256
#define SCAN_I 4
#define SCAN_TILE 1024
#define NTILES ((N_NODES + SCAN_TILE - 1) / SCAN_TILE)   // 98

// ---------------- node prep: h0 = concat(feat, embed[node_ids]); a1/a2 projections
__global__ __launch_bounds__(256) void k_node_prep(
    const float* __restrict__ feat, const int* __restrict__ node_ids,
    const float* __restrict__ embed,
    const float* __restrict__ A1w, const float* __restrict__ A1b,
    const float* __restrict__ A2w, const float* __restrict__ A2b,
    float* __restrict__ h0, float* __restrict__ a1, float* __restrict__ a2) {
  int n = blockIdx.x * blockDim.x + threadIdx.x;
  if (n >= N_NODES) return;
  float h[D0];
  const float4* f4 = reinterpret_cast<const float4*>(feat + (size_t)n * INP);
  #pragma unroll
  for (int i = 0; i < INP / 4; ++i) {
    float4 v = f4[i];
    h[4*i+0] = v.x; h[4*i+1] = v.y; h[4*i+2] = v.z; h[4*i+3] = v.w;
  }
  int nid = node_ids[n];
  const float4* e4 = reinterpret_cast<const float4*>(embed + (size_t)nid * EMB);
  #pragma unroll
  for (int i = 0; i < EMB / 4; ++i) {
    float4 v = e4[i];
    h[INP+4*i+0] = v.x; h[INP+4*i+1] = v.y; h[INP+4*i+2] = v.z; h[INP+4*i+3] = v.w;
  }
  float4* h04 = reinterpret_cast<float4*>(h0 + (size_t)n * D0);
  #pragma unroll
  for (int i = 0; i < D0 / 4; ++i)
    h04[i] = make_float4(h[4*i], h[4*i+1], h[4*i+2], h[4*i+3]);
  for (int o = 0; o < ATTN; ++o) {
    float acc = A1b[o];
    #pragma unroll
    for (int i = 0; i < D0; ++i) acc += h[i] * A1w[o * D0 + i];
    a1[(size_t)n * ATTN + o] = acc;
  }
  for (int o = 0; o < ATTN; ++o) {
    float acc = A2b[o];
    #pragma unroll
    for (int i = 0; i < D0; ++i) acc += h[i] * A2w[o * D0 + i];
    a2[(size_t)n * ATTN + o] = acc;
  }
}

// ---------------- per-edge attention weight
__global__ __launch_bounds__(256) void k_alpha(
    const int* __restrict__ src, const int* __restrict__ dst, const int* __restrict__ typ,
    const float* __restrict__ a1, const float* __restrict__ a2,
    const float* __restrict__ rel, float* __restrict__ alpha) {
  int e = blockIdx.x * blockDim.x + threadIdx.x;
  if (e >= N_EDGES) return;
  int s = src[e], d = dst[e], t = typ[e];
  const float4* p1 = reinterpret_cast<const float4*>(a1 + (size_t)s * ATTN);
  const float4* p2 = reinterpret_cast<const float4*>(a2 + (size_t)d * ATTN);
  const float4* pr = reinterpret_cast<const float4*>(rel + (size_t)t * ATTN);
  float ss = 0.f;
  #pragma unroll
  for (int j = 0; j < ATTN / 4; ++j) {
    float4 x1 = p1[j], x2 = p2[j], xr = pr[j];
    float dx = x1.x + xr.x - x2.x; ss += dx * dx;
    dx = x1.y + xr.y - x2.y; ss += dx * dx;
    dx = x1.z + xr.z - x2.z; ss += dx * dx;
    dx = x1.w + xr.w - x2.w; ss += dx * dx;
  }
  float nrm = sqrtf(ss + 1e-12f);
  alpha[e] = 1.f / (1.f + __expf(nrm - GAMMA_C));
}

// ---------------- CSR build: histogram of dst
__global__ __launch_bounds__(256) void k_hist(const int* __restrict__ dst, int* __restrict__ cnt) {
  int e = blockIdx.x * blockDim.x + threadIdx.x;
  if (e >= N_EDGES) return;
  atomicAdd(&cnt[dst[e]], 1);
}

// block-local exclusive scan; writes block-exclusive values + per-block sums
__global__ __launch_bounds__(SCAN_T) void k_scan1(const int* __restrict__ cnt,
                                                  int* __restrict__ excl, int* __restrict__ bsum) {
  __shared__ int sd[SCAN_T];
  int blk = blockIdx.x, tid = threadIdx.x;
  int base = blk * SCAN_TILE + tid * SCAN_I;
  int v[SCAN_I]; int s = 0;
  #pragma unroll
  for (int i = 0; i < SCAN_I; ++i) { int idx = base + i; v[i] = (idx < N_NODES) ? cnt[idx] : 0; s += v[i]; }
  sd[tid] = s; __syncthreads();
  for (int off = 1; off < SCAN_T; off <<= 1) {
    int t = (tid >= off) ? sd[tid - off] : 0;
    __syncthreads();
    sd[tid] += t;
    __syncthreads();
  }
  int run = sd[tid] - s;   // exclusive prefix of this thread within block
  #pragma unroll
  for (int i = 0; i < SCAN_I; ++i) { int idx = base + i; if (idx < N_NODES) excl[idx] = run; run += v[i]; }
  if (tid == SCAN_T - 1) bsum[blk] = sd[tid];
}

__global__ __launch_bounds__(128) void k_scan2(int* __restrict__ bsum) {
  __shared__ int sd[128];
  int tid = threadIdx.x;
  int v = (tid < NTILES) ? bsum[tid] : 0;
  sd[tid] = v; __syncthreads();
  for (int off = 1; off < 128; off <<= 1) {
    int t = (tid >= off) ? sd[tid - off] : 0;
    __syncthreads();
    sd[tid] += t;
    __syncthreads();
  }
  if (tid < NTILES) bsum[tid] = sd[tid] - v;   // exclusive
}

__global__ __launch_bounds__(256) void k_scan3(int* __restrict__ row_start, int* __restrict__ cursor,
                                               const int* __restrict__ bsum) {
  int i = blockIdx.x * blockDim.x + threadIdx.x;
  if (i < N_NODES) {
    int v = row_start[i] + bsum[i / SCAN_TILE];
    row_start[i] = v; cursor[i] = v;
  }
  if (i == 0) row_start[N_NODES] = N_EDGES;
}

// scatter edges into dst-sorted order
__global__ __launch_bounds__(256) void k_scatter(
    const int* __restrict__ src, const int* __restrict__ dst, const int* __restrict__ typ,
    const float* __restrict__ alpha, int* __restrict__ cursor,
    int* __restrict__ s_src, int* __restrict__ s_typ, float* __restrict__ s_alpha) {
  int e = blockIdx.x * blockDim.x + threadIdx.x;
  if (e >= N_EDGES) return;
  int d = dst[e];
  int pos = atomicAdd(&cursor[d], 1);
  s_src[pos] = src[e];
  s_typ[pos] = typ[e];
  s_alpha[pos] = alpha[e];
}

// ---------------- per-node layer compute: hb[n,b,:] = h@bases[b]; selfbuf[n,:] = h@sloop + bias
template <int DIN>
__global__ __launch_bounds__(256) void k_node_layer(
    const float* __restrict__ hin, const float* __restrict__ bases,
    const float* __restrict__ sloop, const float* __restrict__ bias,
    float* __restrict__ hb, float* __restrict__ selfbuf) {
  int n = blockIdx.x * blockDim.x + threadIdx.x;
  if (n >= N_NODES) return;
  float h[DIN];
  const float4* h4 = reinterpret_cast<const float4*>(hin + (size_t)n * DIN);
  #pragma unroll
  for (int i = 0; i < DIN / 4; ++i) {
    float4 v = h4[i];
    h[4*i+0] = v.x; h[4*i+1] = v.y; h[4*i+2] = v.z; h[4*i+3] = v.w;
  }
  float acc[EMB];
  for (int b = 0; b < NB; ++b) {
    #pragma unroll
    for (int o = 0; o < EMB; ++o) acc[o] = 0.f;
    for (int i = 0; i < DIN; ++i) {
      float hv = h[i];
      #pragma unroll
      for (int o = 0; o < EMB; ++o) acc[o] += hv * bases[((b * DIN) + i) * EMB + o];
    }
    float4* o4 = reinterpret_cast<float4*>(hb + (size_t)n * (NB * EMB) + b * EMB);
    #pragma unroll
    for (int j = 0; j < EMB / 4; ++j)
      o4[j] = make_float4(acc[4*j], acc[4*j+1], acc[4*j+2], acc[4*j+3]);
  }
  #pragma unroll
  for (int o = 0; o < EMB; ++o) acc[o] = bias[o];
  for (int i = 0; i < DIN; ++i) {
    float hv = h[i];
    #pragma unroll
    for (int o = 0; o < EMB; ++o) acc[o] += hv * sloop[i * EMB + o];
  }
  float4* ob = reinterpret_cast<float4*>(selfbuf + (size_t)n * EMB);
  #pragma unroll
  for (int j = 0; j < EMB / 4; ++j)
    ob[j] = make_float4(acc[4*j], acc[4*j+1], acc[4*j+2], acc[4*j+3]);
}

// ---------------- segmented aggregation: one wave per dst node, no atomics
// lane = (half<<5)|c : half-wave 0 takes even edges, half-wave 1 odd edges, c = channel
__global__ __launch_bounds__(256) void k_edge_seg(
    const int* __restrict__ row_start,
    const int* __restrict__ s_src, const int* __restrict__ s_typ, const float* __restrict__ s_alpha,
    const float* __restrict__ wcomp, const float* __restrict__ hb,
    const float* __restrict__ selfbuf, float* __restrict__ outp) {
  int wave = (blockIdx.x * blockDim.x + threadIdx.x) >> 6;
  int lane = threadIdx.x & 63;
  if (wave >= N_NODES) return;
  int beg = row_start[wave], end = row_start[wave + 1];
  int half = lane >> 5, c = lane & 31;
  float acc = 0.f;
  for (int e = beg + half; e < end; e += 2) {
    int s = s_src[e];
    int t = s_typ[e];
    float a = s_alpha[e];
    const float* w = wcomp + (size_t)t * NB;
    float w0 = a * w[0], w1 = a * w[1], w2 = a * w[2], w3 = a * w[3];
    const float* hr = hb + (size_t)s * (NB * EMB);
    acc += w0 * hr[c] + w1 * hr[32 + c] + w2 * hr[64 + c] + w3 * hr[96 + c];
  }
  acc += __shfl(acc, lane ^ 32);
  if (lane < 32) {
    size_t o = (size_t)wave * EMB + c;
    outp[o] = fmaxf(selfbuf[o] + acc, 0.f);
  }
}

extern "C" void kernel_launch(void* const* d_in, const int* in_sizes, int n_in,
                              void* d_out, int out_size, void* d_ws, size_t ws_size,
                              hipStream_t stream) {
  const float* feat     = (const float*)d_in[0];
  const int*   node_ids = (const int*)d_in[1];
  const int*   esrc     = (const int*)d_in[2];
  const int*   edst     = (const int*)d_in[3];
  const int*   etyp     = (const int*)d_in[4];
  const float* embed    = (const float*)d_in[5];
  const float* attn_rel = (const float*)d_in[6];
  const float* A1w = (const float*)d_in[7];
  const float* A1b = (const float*)d_in[8];
  const float* A2w = (const float*)d_in[9];
  const float* A2b = (const float*)d_in[10];
  const float* bases0 = (const float*)d_in[11];
  const float* wcomp0 = (const float*)d_in[12];
  const float* sloop0 = (const float*)d_in[13];
  const float* bias0  = (const float*)d_in[14];
  const float* bases1 = (const float*)d_in[15];
  const float* wcomp1 = (const float*)d_in[16];
  const float* sloop1 = (const float*)d_in[17];
  const float* bias1  = (const float*)d_in[18];
  const float* bases2 = (const float*)d_in[19];
  const float* wcomp2 = (const float*)d_in[20];
  const float* sloop2 = (const float*)d_in[21];
  const float* bias2  = (const float*)d_in[22];

  float* ws = (float*)d_ws;
  // Region A: h0 (N*48 = 4.8M floats), dead after L0 node kernel;
  //           then reused for sorted edge arrays (3 x 1.6M)
  float* h0      = ws;
  int*   s_src   = (int*)ws;
  int*   s_typ   = (int*)(ws + 1600000);
  float* s_alpha = ws + 3200000;
  // Region B: HB (N*128 = 12.8M). a1/a2 alias inside (dead before L0 node kernel).
  float* HB = ws + 4800000;
  float* a1 = HB;
  float* a2 = HB + 3200000;
  // Region C: selfbuf / layer output (N*32 = 3.2M), updated in place by edge kernel
  float* selfbuf = ws + 17600000;
  // Region D: alpha (E = 1.6M), dead after scatter
  float* alpha = ws + 20800000;
  // Region E: CSR metadata
  int* counts    = (int*)(ws + 22400000);   // N
  int* row_start = (int*)(ws + 22500000);   // N+1
  int* cursor    = (int*)(ws + 22600002);   // N
  int* bsum      = (int*)(ws + 22700002);   // NTILES (98)
  float* out = (float*)d_out;

  dim3 blk(256);
  int nb_n = (N_NODES + 255) / 256;
  int nb_e = (N_EDGES + 255) / 256;
  int nb_w = (N_NODES * 64) / 256;          // one wave per node, 4 waves/block

  k_node_prep<<<nb_n, blk, 0, stream>>>(feat, node_ids, embed, A1w, A1b, A2w, A2b, h0, a1, a2);
  k_alpha<<<nb_e, blk, 0, stream>>>(esrc, edst, etyp, a1, a2, attn_rel, alpha);

  // CSR build (row_start/cursor from dst histogram)
  hipMemsetAsync(counts, 0, N_NODES * sizeof(int), stream);
  k_hist<<<nb_e, blk, 0, stream>>>(edst, counts);
  k_scan1<<<NTILES, SCAN_T, 0, stream>>>(counts, row_start, bsum);
  k_scan2<<<1, 128, 0, stream>>>(bsum);
  k_scan3<<<nb_n, blk, 0, stream>>>(row_start, cursor, bsum);

  // layer 0 node compute first (frees h0), then scatter into its region
  k_node_layer<D0><<<nb_n, blk, 0, stream>>>(h0, bases0, sloop0, bias0, HB, selfbuf);
  k_scatter<<<nb_e, blk, 0, stream>>>(esrc, edst, etyp, alpha, cursor, s_src, s_typ, s_alpha);
  k_edge_seg<<<nb_w, blk, 0, stream>>>(row_start, s_src, s_typ, s_alpha, wcomp0, HB, selfbuf, selfbuf);

  // layer 1
  k_node_layer<EMB><<<nb_n, blk, 0, stream>>>(selfbuf, bases1, sloop1, bias1, HB, selfbuf);
  k_edge_seg<<<nb_w, blk, 0, stream>>>(row_start, s_src, s_typ, s_alpha, wcomp1, HB, selfbuf, selfbuf);

  // layer 2 -> d_out
  k_node_layer<EMB><<<nb_n, blk, 0, stream>>>(selfbuf, bases2, sloop2, bias2, HB, selfbuf);
  k_edge_seg<<<nb_w, blk, 0, stream>>>(row_start, s_src, s_typ, s_alpha, wcomp2, HB, selfbuf, out);
}